// Round 1
// baseline (198.214 us; speedup 1.0000x reference)
//
#include <hip/hip_runtime.h>

// ShiftImgPreprocessor: out[b,t,c,i,j] = img[b,t,c, clamp(i+sy-4,0,95), clamp(j+sx-4,0,95)] / 255 - 0.5
//
// Memory-bound clamped gather, dx/dy block-uniform (one b per blockIdx.y).
// v2 structure (this round):
//  - Each thread gathers FOUR plane-strided float4s (planes tcl, tcl+3, tcl+6,
//    tcl+9). Same (i, yy, j4) for all four -> one set of index math, four
//    independent global_load_dwordx4 in flight (4x read MLP vs v1; v1 was
//    latency-bound: ~58us vs ~36us roofline for 226.5 MB of traffic).
//  - Single UNALIGNED 16B load per gather (HW handles 4B alignment) replaces
//    v1's two aligned loads + phase switch: halves load instrs + L1 traffic.
//  - Edge lanes (j4==0 with dx<0, j4==23 with dx>0): e = s - clamp(s,0,92)
//    equals dx exactly, which is SGPR-uniform -> replicate-clamp fixup is a
//    scalar switch selecting a fixed component swizzle (v_movs under exec
//    mask), not scalar gathers / cndmask chains.

#define PAD 4
#define NB  256   // batch
#define TT  4
#define CC  3
#define HH  96
#define WW  96
#define W4  (WW / 4)                    // 24 float4 per row
#define TC  (TT * CC)                   // 12 planes per batch element
#define QQ  4                           // gathers per thread (plane stride 3)
#define TCL (TC / QQ)                   // 3 "local" plane indices per thread
#define VQ  (TCL * HH * W4)             // 6912 float4-slots handled per batch per q=0
#define BLOCK 256

typedef float vfloat4 __attribute__((ext_vector_type(4)));

__device__ __forceinline__ vfloat4 loadu4(const float* p) {
    // 4B-aligned 16B load; gfx950 unaligned-access mode emits one global_load_dwordx4
    vfloat4 r;
    __builtin_memcpy(&r, __builtin_assume_aligned(p, 4), sizeof(r));
    return r;
}

__global__ __launch_bounds__(BLOCK) void ShiftImgPreprocessor_36679020708143_kernel(
    const float* __restrict__ img,
    const int*   __restrict__ shift,
    float*       __restrict__ out)
{
    const int b = blockIdx.y;
    const int v = blockIdx.x * BLOCK + threadIdx.x;   // [0, VQ) = [0, 6912)

    const int j4  = v % W4;          // which float4 in the row
    const int r_  = v / W4;          // [0, TCL*HH) = [0, 288)
    const int i   = r_ % HH;         // output row
    const int tcl = r_ / HH;         // local plane index [0,3)

    // block-uniform -> SGPR loads
    const int dx = shift[2 * b + 0] - PAD;   // in [-4, 4]
    const int dy = shift[2 * b + 1] - PAD;

    const int yy = min(max(i + dy, 0), HH - 1);

    const int j  = j4 * 4;
    const int s  = j + dx;                     // [-4, 96]
    const int sc = min(max(s, 0), WW - 4);     // clamped load base, [0, 92]
    const int e  = s - sc;                     // 0 interior; == dx on edge lanes

    const size_t HW   = (size_t)HH * WW;
    const size_t base = ((size_t)b * TC + tcl) * HW;
    const size_t pq   = (size_t)TCL * HW;      // 3 planes between the 4 gathers

    const float* __restrict__ src0 = img + base + (size_t)yy * WW + sc;
    float*       __restrict__ dst0 = out + base + (size_t)i  * WW + j;

    // four independent reads in flight
    vfloat4 V0 = loadu4(src0);
    vfloat4 V1 = loadu4(src0 + pq);
    vfloat4 V2 = loadu4(src0 + 2 * pq);
    vfloat4 V3 = loadu4(src0 + 3 * pq);

    if (e != 0) {
        // horizontal replicate-clamp: out_k = V[clamp(e+k,0,3)], and e == dx
        // (uniform) on all active lanes -> scalar-branched fixed swizzle.
        #define FIXUP(c0, c1, c2, c3)                              \
            V0 = (vfloat4){V0.c0, V0.c1, V0.c2, V0.c3};            \
            V1 = (vfloat4){V1.c0, V1.c1, V1.c2, V1.c3};            \
            V2 = (vfloat4){V2.c0, V2.c1, V2.c2, V2.c3};            \
            V3 = (vfloat4){V3.c0, V3.c1, V3.c2, V3.c3};            \
            break;
        switch (dx) {
            case -4: FIXUP(x, x, x, x)
            case -3: FIXUP(x, x, x, x)
            case -2: FIXUP(x, x, x, y)
            case -1: FIXUP(x, x, y, z)
            case  1: FIXUP(y, z, w, w)
            case  2: FIXUP(z, w, w, w)
            case  3: FIXUP(w, w, w, w)
            default: FIXUP(w, w, w, w)   // dx == 4
        }
        #undef FIXUP
    }

    const float k = 1.0f / 255.0f;
    V0 = V0 * k - 0.5f;
    V1 = V1 * k - 0.5f;
    V2 = V2 * k - 0.5f;
    V3 = V3 * k - 0.5f;

    __builtin_nontemporal_store(V0, (vfloat4*)(dst0));
    __builtin_nontemporal_store(V1, (vfloat4*)(dst0 + pq));
    __builtin_nontemporal_store(V2, (vfloat4*)(dst0 + 2 * pq));
    __builtin_nontemporal_store(V3, (vfloat4*)(dst0 + 3 * pq));
}

extern "C" void kernel_launch(void* const* d_in, const int* in_sizes, int n_in,
                              void* d_out, int out_size, void* d_ws, size_t ws_size,
                              hipStream_t stream) {
    const float* img   = (const float*)d_in[0];
    const int*   shift = (const int*)d_in[1];
    float*       out   = (float*)d_out;

    dim3 grid(VQ / BLOCK, NB);   // (27, 256) = 6912 workgroups, 4 waves each
    ShiftImgPreprocessor_36679020708143_kernel<<<grid, BLOCK, 0, stream>>>(img, shift, out);
}

// Round 4
// 196.069 us; speedup vs baseline: 1.0109x; 1.0109x over previous
//
#include <hip/hip_runtime.h>

// ShiftImgPreprocessor: out[b,t,c,i,j] = img[b,t,c, clamp(i+sy-4,0,95), clamp(j+sx-4,0,95)] / 255 - 0.5
//
// v3 (2nd resubmit; rounds 2-3 died on container acquisition infra, kernel
// never ran; source audited memory-safe: a0,a1 in [0,23], planes <= b*12+11):
//  - v1 (59us): two ALIGNED dwordx4 + uniform-phase select, 1 output/thread.
//  - v2 (67us, REGRESSION): single UNALIGNED dwordx4, 4 outputs/thread. The
//    4B-misaligned 16B loads hit the slow path (line-crossing/sub-dword),
//    multiplying L1/TA transactions - cost more than the 4x MLP gained.
//  - v3 merges the winning halves: per thread, FOUR plane-strided outputs
//    (planes tcl, tcl+3, tcl+6, tcl+9 share all index math), each produced
//    from two ALIGNED dwordx4 (A=sv[a4], B=sv[a4+1]) blended by the
//    wave-uniform phase r = dx&3 (scalar branch, pure v_movs). 8 independent
//    aligned loads in flight per thread. When r==0 (dx in {-4,0,4}; 3 of 9
//    values) the B loads are skipped entirely (uniform branch).
//  - Edge lanes (j4==0 && dx<0 | j4==23 && dx>0): replicate-clamp is a
//    uniform-dx fixed component swizzle of the clamped aligned vector A
//    (table verified in v2 run: absmax stayed at the rounding floor 2^-10).
//
// Roofline: steady-state FETCH=55MB (input ~50% L3-resident) + WRITE=110MB
// -> ~27us floor at 6.3TB/s. v2 measured 67us @ 2.5TB/s => latency/transaction
// bound, not BW/VALU/occupancy (VALUBusy 5.5%, occ 62%, 0 bank conflicts).

#define PAD 4
#define NB  256   // batch
#define TT  4
#define CC  3
#define HH  96
#define WW  96
#define W4  (WW / 4)                    // 24 float4 per row
#define TC  (TT * CC)                   // 12 planes per batch element
#define QQ  4                           // outputs per thread (plane stride 3)
#define TCL (TC / QQ)                   // 3 local plane indices
#define VQ  (TCL * HH * W4)             // 6912 float4-slots per batch at q=0
#define BLOCK 256

typedef float vfloat4 __attribute__((ext_vector_type(4)));

__global__ __launch_bounds__(BLOCK) void ShiftImgPreprocessor_36679020708143_kernel(
    const float* __restrict__ img,
    const int*   __restrict__ shift,
    float*       __restrict__ out)
{
    const int b = blockIdx.y;
    const int v = blockIdx.x * BLOCK + threadIdx.x;   // [0, VQ)

    const int j4  = v % W4;          // float4 index in row
    const int r_  = v / W4;          // [0, TCL*HH)
    const int i   = r_ % HH;         // output row
    const int tcl = r_ / HH;         // local plane [0,3)

    // block-uniform -> SGPR
    const int dx = shift[2 * b + 0] - PAD;   // [-4, 4]
    const int dy = shift[2 * b + 1] - PAD;

    const int yy = min(max(i + dy, 0), HH - 1);

    const int j  = j4 * 4;
    const int s  = j + dx;                    // [-4, 96]
    const int a4 = s >> 2;                    // arithmetic: [-1, 24]
    const int a0 = min(max(a4, 0), W4 - 1);   // clamped aligned base
    const int a1 = min(a4 + 1, W4 - 1);

    const size_t HW   = (size_t)HH * WW;
    const size_t base = ((size_t)b * TC + tcl) * HW;
    const size_t pq   = (size_t)TCL * HW;     // 3 planes between the 4 outputs

    const float* __restrict__ srow = img + base + (size_t)yy * WW;
    const vfloat4* __restrict__ s0 = (const vfloat4*)(srow);
    const vfloat4* __restrict__ s1 = (const vfloat4*)(srow + pq);
    const vfloat4* __restrict__ s2 = (const vfloat4*)(srow + 2 * pq);
    const vfloat4* __restrict__ s3 = (const vfloat4*)(srow + 3 * pq);

    // four independent ALIGNED reads (A side) in flight
    vfloat4 A0 = s0[a0], A1 = s1[a0], A2 = s2[a0], A3 = s3[a0];

    const int r = dx & 3;   // wave-uniform phase
    vfloat4 O0, O1, O2, O3;

    if (r == 0) {
        // dx in {-4, 0, 4}: pure aligned copy (edge fixup below handles +-4 rims)
        O0 = A0; O1 = A1; O2 = A2; O3 = A3;
    } else {
        // B side: four more independent aligned reads
        vfloat4 B0 = s0[a1], B1 = s1[a1], B2 = s2[a1], B3 = s3[a1];
        switch (r) {   // scalar branch on uniform r -> fixed component blends
            case 1:
                O0 = (vfloat4){A0.y, A0.z, A0.w, B0.x};
                O1 = (vfloat4){A1.y, A1.z, A1.w, B1.x};
                O2 = (vfloat4){A2.y, A2.z, A2.w, B2.x};
                O3 = (vfloat4){A3.y, A3.z, A3.w, B3.x};
                break;
            case 2:
                O0 = (vfloat4){A0.z, A0.w, B0.x, B0.y};
                O1 = (vfloat4){A1.z, A1.w, B1.x, B1.y};
                O2 = (vfloat4){A2.z, A2.w, B2.x, B2.y};
                O3 = (vfloat4){A3.z, A3.w, B3.x, B3.y};
                break;
            default:
                O0 = (vfloat4){A0.w, B0.x, B0.y, B0.z};
                O1 = (vfloat4){A1.w, B1.x, B1.y, B1.z};
                O2 = (vfloat4){A2.w, B2.x, B2.y, B2.z};
                O3 = (vfloat4){A3.w, B3.x, B3.y, B3.z};
                break;
        }
    }

    if (s < 0 || s > WW - 4) {
        // edge float4 (j4==0 && dx<0, or j4==23 && dx>0): replicate-clamp.
        // A = src[0..3] (left, a0=0) or src[92..95] (right, a0=23).
        // out_k = A[clamp(dx+k, 0, 3)] relative to the clamped base.
        #define FIXUP(c0, c1, c2, c3)                              \
            O0 = (vfloat4){A0.c0, A0.c1, A0.c2, A0.c3};            \
            O1 = (vfloat4){A1.c0, A1.c1, A1.c2, A1.c3};            \
            O2 = (vfloat4){A2.c0, A2.c1, A2.c2, A2.c3};            \
            O3 = (vfloat4){A3.c0, A3.c1, A3.c2, A3.c3};            \
            break;
        switch (dx) {   // wave-uniform
            case -4: FIXUP(x, x, x, x)
            case -3: FIXUP(x, x, x, x)
            case -2: FIXUP(x, x, x, y)
            case -1: FIXUP(x, x, y, z)
            case  1: FIXUP(y, z, w, w)
            case  2: FIXUP(z, w, w, w)
            case  3: FIXUP(w, w, w, w)
            default: FIXUP(w, w, w, w)   // dx == 4
        }
        #undef FIXUP
    }

    const float k = 1.0f / 255.0f;
    O0 = O0 * k - 0.5f;
    O1 = O1 * k - 0.5f;
    O2 = O2 * k - 0.5f;
    O3 = O3 * k - 0.5f;

    float* __restrict__ drow = out + base + (size_t)i * WW + j;
    __builtin_nontemporal_store(O0, (vfloat4*)(drow));
    __builtin_nontemporal_store(O1, (vfloat4*)(drow + pq));
    __builtin_nontemporal_store(O2, (vfloat4*)(drow + 2 * pq));
    __builtin_nontemporal_store(O3, (vfloat4*)(drow + 3 * pq));
}

extern "C" void kernel_launch(void* const* d_in, const int* in_sizes, int n_in,
                              void* d_out, int out_size, void* d_ws, size_t ws_size,
                              hipStream_t stream) {
    const float* img   = (const float*)d_in[0];
    const int*   shift = (const int*)d_in[1];
    float*       out   = (float*)d_out;

    dim3 grid(VQ / BLOCK, NB);   // (27, 256)
    ShiftImgPreprocessor_36679020708143_kernel<<<grid, BLOCK, 0, stream>>>(img, shift, out);
}

// Round 5
// 193.954 us; speedup vs baseline: 1.0220x; 1.0109x over previous
//
#include <hip/hip_runtime.h>

// ShiftImgPreprocessor: out[b,t,c,i,j] = img[b,t,c, clamp(i+sy-4,0,95), clamp(j+sx-4,0,95)] / 255 - 0.5
//
// v4 = v1 (best known: ~58.6us kernel) with ONE change: plain stores instead
// of __builtin_nontemporal_store.
//
// Evidence chain:
//  - v1 (1 out/thr, dual aligned load + uniform blend, NT): ~58.6us
//  - v2 (4 out/thr, unaligned loads, NT): 67.2us
//  - v3 (4 out/thr, dual aligned loads, NT): 66.8us  (v2==v3 -> load structure
//    irrelevant; v3-v1 gap = wave-count tail: 3.4 residency rounds vs 13.5)
//  - All three: ~2.5-2.9 TB/s HBM, VALUBusy ~6%, 0 conflicts. Meanwhile the
//    harness fill kernel does 6.8 TB/s pure writes at 9% occupancy / 8 VGPRs.
//  - The one untested invariant: NT stores. Theory: nt (no-allocate) forces
//    the 110MB write stream to bypass L2/L3 and commit fine-grained to DRAM,
//    interleaving with reads; plain write-allocate lets L2/L3 absorb+drain in
//    bulk (the fill and the 6.29TB/s m13 copy both use the normal path).
// Prediction: kernel -> 35-45us (4.5-5.5 TB/s) if theory right; unchanged if
// wrong (then next: isolate read-only vs write-only stream rates).

#define PAD 4
#define NB  256   // batch
#define TT  4
#define CC  3
#define HH  96
#define WW  96
#define W4  (WW / 4)                    // 24 float4 per row
#define ROWS_PER_B (TT * CC * HH)       // 1152
#define V4_PER_B (ROWS_PER_B * W4)      // 27648 float4 per batch
#define BLOCK 256

typedef float vfloat4 __attribute__((ext_vector_type(4)));

__global__ __launch_bounds__(BLOCK) void ShiftImgPreprocessor_36679020708143_kernel(
    const float* __restrict__ img,
    const int*   __restrict__ shift,
    float*       __restrict__ out)
{
    const int b = blockIdx.y;
    const int v = blockIdx.x * BLOCK + threadIdx.x;   // [0, V4_PER_B)

    const int j4 = v % W4;           // which float4 in the row
    const int r_ = v / W4;           // row index within batch: [0, T*C*H)
    const int i  = r_ % HH;          // output row
    const int tc = r_ / HH;          // fused (t,c) plane index

    // block-uniform -> SGPR loads
    const int dx = shift[2 * b + 0] - PAD;   // in [-4, 4]
    const int dy = shift[2 * b + 1] - PAD;

    const int yy = min(max(i + dy, 0), HH - 1);

    const size_t plane = ((size_t)b * (TT * CC) + tc) * (size_t)(HH * WW);
    const float* __restrict__ srcrow = img + plane + (size_t)yy * WW;

    const int j = j4 * 4;
    const float k = 1.0f / 255.0f;
    vfloat4 o;

    if (j4 == 0 || j4 == W4 - 1) {
        // edge float4: may need horizontal clamping -> scalar clamped gather
        const int x0 = min(max(j + 0 + dx, 0), WW - 1);
        const int x1 = min(max(j + 1 + dx, 0), WW - 1);
        const int x2 = min(max(j + 2 + dx, 0), WW - 1);
        const int x3 = min(max(j + 3 + dx, 0), WW - 1);
        o = (vfloat4){srcrow[x0], srcrow[x1], srcrow[x2], srcrow[x3]};
    } else {
        // interior: s = j+dx in [0,92]; source floats s..s+3 live in vecs a4, a4+1
        const int s  = j + dx;
        const int a4 = s >> 2;                 // consecutive lanes -> consecutive vecs
        const int r  = dx & 3;                 // SGPR-uniform phase -> scalar branch
        const vfloat4* __restrict__ sv = (const vfloat4*)srcrow;
        const vfloat4 V0 = sv[a4];
        const vfloat4 V1 = sv[min(a4 + 1, W4 - 1)];   // unused when r==0; clamp avoids OOB
        switch (r) {
            case 0:  o = V0; break;
            case 1:  o = (vfloat4){V0.y, V0.z, V0.w, V1.x}; break;
            case 2:  o = (vfloat4){V0.z, V0.w, V1.x, V1.y}; break;
            default: o = (vfloat4){V0.w, V1.x, V1.y, V1.z}; break;
        }
    }

    o = o * k - 0.5f;

    // v4 change: PLAIN store (write-allocate path; L2/L3 absorb the stream)
    vfloat4* outv = (vfloat4*)(out + plane + (size_t)i * WW + j);
    *outv = o;
}

extern "C" void kernel_launch(void* const* d_in, const int* in_sizes, int n_in,
                              void* d_out, int out_size, void* d_ws, size_t ws_size,
                              hipStream_t stream) {
    const float* img   = (const float*)d_in[0];
    const int*   shift = (const int*)d_in[1];
    float*       out   = (float*)d_out;

    dim3 grid(V4_PER_B / BLOCK, NB);   // (108, 256)
    ShiftImgPreprocessor_36679020708143_kernel<<<grid, BLOCK, 0, stream>>>(img, shift, out);
}